// Round 11
// baseline (52.896 us; speedup 1.0000x reference)
//
#include <hip/hip_runtime.h>
#include <hip/hip_fp16.h>
#include <math.h>

#define N_DENSE 13
#define N_SPARSE 26
#define SPARSE_DIM 100
#define N_FIELD 39               // 13 + 26 real fields
#define KDIM 16
#define N_FEATURES 2613          // 13 + 26*100
#define ROW_F 624                // real elements per feature row (39*16)
#define ROW_DW 320               // padded half2 per row (40 fields * 8 k-pairs)
#define ROW_BYTES 1280
#define THREADS 256
#define ROWS_PER_BLOCK 4         // one 64-lane wave per row

// ---------------- pre-pass: fp32 -> half2, padded to 40 fields --------------
__global__ __launch_bounds__(ROW_DW) void cvt_pad_f16(
    const float* __restrict__ v, __half2* __restrict__ o)
{
    int n = blockIdx.x;
    int d = threadIdx.x;
    __half2 r = __floats2half2_rn(0.f, 0.f);
    if (d < ROW_F / 2) {
        float2 f = *reinterpret_cast<const float2*>(v + (size_t)n * ROW_F + 2 * d);
        r = __floats2half2_rn(f.x, f.y);
    }
    o[(size_t)n * ROW_DW + d] = r;
}

__device__ __forceinline__ __half2 h2(unsigned int v) {
    return *reinterpret_cast<__half2*>(&v);
}

// ---------------- main kernel: one wave per batch row -----------------------
// Row image: 320 dwords (half2); dword d: field f = d>>3, k-pair j = d&7.
// Lane l (t = l>>2, p = l&3, u = t&1):
//   A: uint2 @ byte 8l      -> field t,        k = 4p..4p+3
//   B: uint2 @ byte 512+8l  -> field 16+t,     k = 4p..4p+3
//   C: dword @ byte 1024+32*(t>>1)+8p+4u -> field 32+(t>>1), k = 4p+2u, 4p+2u+1
//      (bijective lane->dword within the 256B segment; stays coalesced)
// 3 wave-requests/feature (vs 5 dword) with IDENTICAL bytes (1280/feature).
// Orbit {4,8,16,32} (16 lanes, same p): A covers fields 0..15, B 16..31,
// C 32..39 with u=0 filling k-slots 0,1 and u=1 slots 2,3. Stage-2 {1,2}
// merges the 4 p-classes. lin is scalar (v10 pattern).
// launch_bounds(256,7): same 20-dword group payload as v10 (no spill there).
__global__ __launch_bounds__(THREADS, 7) void ffm_v11(
    const float* __restrict__ x,     // [B, 39]
    const float* __restrict__ w,     // [2613]
    const float* __restrict__ bias,  // [1]
    const __half2* __restrict__ vb,  // [2613, 320] padded half2 rows
    float* __restrict__ out,         // [B]
    int B)
{
    __shared__ __half2 ldsDense[N_DENSE * ROW_DW];   // 16640 B
    {
        const uint4* src = reinterpret_cast<const uint4*>(vb);
        uint4* dst = reinterpret_cast<uint4*>(ldsDense);
        for (int i = threadIdx.x; i < N_DENSE * ROW_DW / 4; i += THREADS)
            dst[i] = src[i];
    }
    __syncthreads();

    const int l = threadIdx.x & 63;
    const int t = l >> 2;
    const int p = l & 3;
    const int u = t & 1;
    const int aOff = 8 * l;
    const int cOff = 1024 + ((t >> 1) << 5) + (p << 3) + (u << 2);

    // wave-uniform wave id -> uniform row -> x reads become s_loads
    const int wv = __builtin_amdgcn_readfirstlane((int)(threadIdx.x >> 6));
    const int row = blockIdx.x * ROWS_PER_BLOCK + wv;
    if (row >= B) return;

    const float* xr = x + (size_t)row * N_FIELD;

    const __half2 zero = __floats2half2_rn(0.f, 0.f);
    __half2 A0 = zero, A1 = zero, B0 = zero, B1 = zero, C = zero;

    float lin = bias[0];

    // ---- dense features (LDS broadcast, uniform xv; fold linear part) ----
#pragma unroll
    for (int j = 0; j < N_DENSE; ++j) {
        float xv = xr[j];
        lin = fmaf(xv, w[j], lin);
        __half2 xh = __float2half2_rn(xv);
        const char* base = reinterpret_cast<const char*>(ldsDense) + j * ROW_BYTES;
        uint2 da = *reinterpret_cast<const uint2*>(base + aOff);
        uint2 db = *reinterpret_cast<const uint2*>(base + 512 + aOff);
        unsigned int dc = *reinterpret_cast<const unsigned int*>(base + cOff);
        A0 = __hfma2(xh, h2(da.x), A0); A1 = __hfma2(xh, h2(da.y), A1);
        B0 = __hfma2(xh, h2(db.x), B0); B1 = __hfma2(xh, h2(db.y), B1);
        C  = __hfma2(xh, h2(dc),   C);
    }

    // ---- sparse gathers: 4 features/group, 12 wide loads (20 dwords) in flight
#pragma unroll
    for (int s = 0; s < 24; s += 4) {
        int i0 = N_DENSE + (s    ) * SPARSE_DIM + (int)xr[N_DENSE + s    ];
        int i1 = N_DENSE + (s + 1) * SPARSE_DIM + (int)xr[N_DENSE + s + 1];
        int i2 = N_DENSE + (s + 2) * SPARSE_DIM + (int)xr[N_DENSE + s + 2];
        int i3 = N_DENSE + (s + 3) * SPARSE_DIM + (int)xr[N_DENSE + s + 3];
        const char* r0 = reinterpret_cast<const char*>(vb) + (size_t)i0 * ROW_BYTES;
        const char* r1 = reinterpret_cast<const char*>(vb) + (size_t)i1 * ROW_BYTES;
        const char* r2 = reinterpret_cast<const char*>(vb) + (size_t)i2 * ROW_BYTES;
        const char* r3 = reinterpret_cast<const char*>(vb) + (size_t)i3 * ROW_BYTES;
        uint2 a0 = *reinterpret_cast<const uint2*>(r0 + aOff);
        uint2 b0 = *reinterpret_cast<const uint2*>(r0 + 512 + aOff);
        unsigned int c0 = *reinterpret_cast<const unsigned int*>(r0 + cOff);
        uint2 a1 = *reinterpret_cast<const uint2*>(r1 + aOff);
        uint2 b1 = *reinterpret_cast<const uint2*>(r1 + 512 + aOff);
        unsigned int c1 = *reinterpret_cast<const unsigned int*>(r1 + cOff);
        uint2 a2 = *reinterpret_cast<const uint2*>(r2 + aOff);
        uint2 b2 = *reinterpret_cast<const uint2*>(r2 + 512 + aOff);
        unsigned int c2 = *reinterpret_cast<const unsigned int*>(r2 + cOff);
        uint2 a3 = *reinterpret_cast<const uint2*>(r3 + aOff);
        uint2 b3 = *reinterpret_cast<const uint2*>(r3 + 512 + aOff);
        unsigned int c3 = *reinterpret_cast<const unsigned int*>(r3 + cOff);
        lin += w[i0] + w[i1] + w[i2] + w[i3];
        A0 = __hadd2(A0, h2(a0.x)); A1 = __hadd2(A1, h2(a0.y));
        B0 = __hadd2(B0, h2(b0.x)); B1 = __hadd2(B1, h2(b0.y));
        C  = __hadd2(C,  h2(c0));
        A0 = __hadd2(A0, h2(a1.x)); A1 = __hadd2(A1, h2(a1.y));
        B0 = __hadd2(B0, h2(b1.x)); B1 = __hadd2(B1, h2(b1.y));
        C  = __hadd2(C,  h2(c1));
        A0 = __hadd2(A0, h2(a2.x)); A1 = __hadd2(A1, h2(a2.y));
        B0 = __hadd2(B0, h2(b2.x)); B1 = __hadd2(B1, h2(b2.y));
        C  = __hadd2(C,  h2(c2));
        A0 = __hadd2(A0, h2(a3.x)); A1 = __hadd2(A1, h2(a3.y));
        B0 = __hadd2(B0, h2(b3.x)); B1 = __hadd2(B1, h2(b3.y));
        C  = __hadd2(C,  h2(c3));
    }
    {   // tail pair: s = 24, 25
        int i0 = N_DENSE + 24 * SPARSE_DIM + (int)xr[N_DENSE + 24];
        int i1 = N_DENSE + 25 * SPARSE_DIM + (int)xr[N_DENSE + 25];
        const char* r0 = reinterpret_cast<const char*>(vb) + (size_t)i0 * ROW_BYTES;
        const char* r1 = reinterpret_cast<const char*>(vb) + (size_t)i1 * ROW_BYTES;
        uint2 a0 = *reinterpret_cast<const uint2*>(r0 + aOff);
        uint2 b0 = *reinterpret_cast<const uint2*>(r0 + 512 + aOff);
        unsigned int c0 = *reinterpret_cast<const unsigned int*>(r0 + cOff);
        uint2 a1 = *reinterpret_cast<const uint2*>(r1 + aOff);
        uint2 b1 = *reinterpret_cast<const uint2*>(r1 + 512 + aOff);
        unsigned int c1 = *reinterpret_cast<const unsigned int*>(r1 + cOff);
        lin += w[i0] + w[i1];
        A0 = __hadd2(A0, h2(a0.x)); A1 = __hadd2(A1, h2(a0.y));
        B0 = __hadd2(B0, h2(b0.x)); B1 = __hadd2(B1, h2(b0.y));
        C  = __hadd2(C,  h2(c0));
        A0 = __hadd2(A0, h2(a1.x)); A1 = __hadd2(A1, h2(a1.y));
        B0 = __hadd2(B0, h2(b1.x)); B1 = __hadd2(B1, h2(b1.y));
        C  = __hadd2(C,  h2(c1));
    }

    // ---- per-lane s/q for k-classes 4p..4p+3 (f32) ----
    float a0l = __low2float(A0), a0h = __high2float(A0);
    float a1l = __low2float(A1), a1h = __high2float(A1);
    float b0l = __low2float(B0), b0h = __high2float(B0);
    float b1l = __low2float(B1), b1h = __high2float(B1);
    float ccl = __low2float(C),  cch = __high2float(C);
    // C belongs to k-slots (2u, 2u+1) of this lane's p-class
    float e0 = u ? 0.f : ccl, e1 = u ? 0.f : cch;
    float e2 = u ? ccl : 0.f, e3 = u ? cch : 0.f;

    float s0 = a0l + b0l + e0;
    float s1 = a0h + b0h + e1;
    float s2 = a1l + b1l + e2;
    float s3 = a1h + b1h + e3;
    float q0 = a0l*a0l + b0l*b0l + e0*e0;
    float q1 = a0h*a0h + b0h*b0h + e1*e1;
    float q2 = a1l*a1l + b1l*b1l + e2*e2;
    float q3 = a1h*a1h + b1h*b1h + e3*e3;

    // ---- stage 1: sum over the 16-lane orbit (same p) ----
#pragma unroll
    for (int m = 4; m <= 32; m <<= 1) {
        s0 += __shfl_xor(s0, m); s1 += __shfl_xor(s1, m);
        s2 += __shfl_xor(s2, m); s3 += __shfl_xor(s3, m);
        q0 += __shfl_xor(q0, m); q1 += __shfl_xor(q1, m);
        q2 += __shfl_xor(q2, m); q3 += __shfl_xor(q3, m);
    }
    float uval = 0.5f * ((s0*s0 - q0) + (s1*s1 - q1) +
                         (s2*s2 - q2) + (s3*s3 - q3));
    // ---- stage 2: merge the 4 p-classes ----
    uval += __shfl_xor(uval, 1);
    uval += __shfl_xor(uval, 2);

    float logit = lin + uval;
    if (l == 0) out[row] = 1.f / (1.f + expf(-logit));
}

// ---------------- fp32 fallback (round-1 kernel, 16 lanes/row) --------------
#define ROW_Q (ROW_F / 4)
__global__ __launch_bounds__(256) void ffm_fp32(
    const float* __restrict__ x, const float* __restrict__ w,
    const float* __restrict__ bias, const float* __restrict__ v,
    float* __restrict__ out, int B)
{
    __shared__ float ldsDense[N_DENSE * ROW_F];
    const float4* v4 = reinterpret_cast<const float4*>(v);
    float4* lds4 = reinterpret_cast<float4*>(ldsDense);
    for (int i = threadIdx.x; i < N_DENSE * ROW_Q; i += 256) lds4[i] = v4[i];
    __syncthreads();

    const int g = threadIdx.x >> 4, l = threadIdx.x & 15;
    const int row = blockIdx.x * 16 + g;
    if (row >= B) return;
    const float* xr = x + row * (N_DENSE + N_SPARSE);

    float4 acc[10];
#pragma unroll
    for (int i = 0; i < 10; ++i) acc[i] = make_float4(0.f, 0.f, 0.f, 0.f);
#pragma unroll
    for (int j = 0; j < N_DENSE; ++j) {
        float xv = xr[j];
        const float4* b = lds4 + j * ROW_Q;
#pragma unroll
        for (int i = 0; i < 10; ++i)
            if (i < 9 || l < 12) {
                float4 tt = b[l + 16 * i];
                acc[i].x += xv * tt.x; acc[i].y += xv * tt.y;
                acc[i].z += xv * tt.z; acc[i].w += xv * tt.w;
            }
    }
    int nidx[N_SPARSE];
#pragma unroll
    for (int s = 0; s < N_SPARSE; ++s)
        nidx[s] = N_DENSE + s * SPARSE_DIM + (int)xr[N_DENSE + s];
    for (int s = 0; s < N_SPARSE; ++s) {
        const float4* b = v4 + (size_t)nidx[s] * ROW_Q;
#pragma unroll
        for (int i = 0; i < 10; ++i)
            if (i < 9 || l < 12) {
                float4 tt = b[l + 16 * i];
                acc[i].x += tt.x; acc[i].y += tt.y; acc[i].z += tt.z; acc[i].w += tt.w;
            }
    }
    float4 s4 = make_float4(0,0,0,0), q4 = make_float4(0,0,0,0);
#pragma unroll
    for (int i = 0; i < 10; ++i) {
        s4.x += acc[i].x; s4.y += acc[i].y; s4.z += acc[i].z; s4.w += acc[i].w;
        q4.x += acc[i].x*acc[i].x; q4.y += acc[i].y*acc[i].y;
        q4.z += acc[i].z*acc[i].z; q4.w += acc[i].w*acc[i].w;
    }
#pragma unroll
    for (int m = 4; m <= 8; m <<= 1) {
        s4.x += __shfl_xor(s4.x,m); s4.y += __shfl_xor(s4.y,m);
        s4.z += __shfl_xor(s4.z,m); s4.w += __shfl_xor(s4.w,m);
        q4.x += __shfl_xor(q4.x,m); q4.y += __shfl_xor(q4.y,m);
        q4.z += __shfl_xor(q4.z,m); q4.w += __shfl_xor(q4.w,m);
    }
    float c = (s4.x*s4.x - q4.x) + (s4.y*s4.y - q4.y) +
              (s4.z*s4.z - q4.z) + (s4.w*s4.w - q4.w);
    c += __shfl_xor(c,1); c += __shfl_xor(c,2);
    float lin = bias[0];
#pragma unroll
    for (int j = 0; j < N_DENSE; ++j) lin += xr[j]*w[j];
#pragma unroll
    for (int s = 0; s < N_SPARSE; ++s) lin += w[nidx[s]];
    float logit = lin + 0.5f*c;
    if (l == 0) out[row] = 1.f/(1.f+expf(-logit));
}

extern "C" void kernel_launch(void* const* d_in, const int* in_sizes, int n_in,
                              void* d_out, int out_size, void* d_ws, size_t ws_size,
                              hipStream_t stream) {
    const float* x    = (const float*)d_in[0];
    const float* w    = (const float*)d_in[1];
    const float* bias = (const float*)d_in[2];
    const float* v    = (const float*)d_in[3];
    float* out = (float*)d_out;

    int B = in_sizes[0] / (N_DENSE + N_SPARSE);
    size_t need = (size_t)N_FEATURES * ROW_DW * sizeof(__half2);  // 3,344,640 B

    if (ws_size >= need) {
        cvt_pad_f16<<<N_FEATURES, ROW_DW, 0, stream>>>(v, (__half2*)d_ws);
        int grid = (B + ROWS_PER_BLOCK - 1) / ROWS_PER_BLOCK;
        ffm_v11<<<grid, THREADS, 0, stream>>>(
            x, w, bias, (const __half2*)d_ws, out, B);
    } else {
        int grid = (B + 15) / 16;
        ffm_fp32<<<grid, 256, 0, stream>>>(x, w, bias, v, out, B);
    }
}

// Round 12
// 36.442 us; speedup vs baseline: 1.4515x; 1.4515x over previous
//
#include <hip/hip_runtime.h>
#include <hip/hip_fp16.h>
#include <math.h>

#define N_DENSE 13
#define N_SPARSE 26
#define SPARSE_DIM 100
#define N_FIELD 39               // 13 + 26 real fields
#define KDIM 16
#define N_FEATURES 2613          // 13 + 26*100
#define ROW_F 624                // real elements per feature row (39*16)
#define ROW_DW 320               // padded half2 per row (40 fields * 8 k-pairs)
#define ROW_U2 160               // uint2 (4 elems) per padded row
#define THREADS 256
#define ROWS_PER_BLOCK 4         // one 64-lane wave per row

// ---------------- pre-pass: fp32 -> half2, padded to 40 fields --------------
// One uint2 (4 elements) per thread, float4 source reads, 256-thread blocks.
#define CVT_TOTAL (N_FEATURES * ROW_U2)
__global__ __launch_bounds__(256) void cvt_pad_f16v(
    const float* __restrict__ v, uint2* __restrict__ o)
{
    int stride = gridDim.x * blockDim.x;
    for (int i = blockIdx.x * blockDim.x + threadIdx.x; i < CVT_TOTAL; i += stride) {
        int n = i / ROW_U2;
        int r = i - n * ROW_U2;      // uint2 index within row
        uint2 w2 = make_uint2(0u, 0u);
        int e = 4 * r;               // first element (of 640 padded; 624 real)
        if (e < ROW_F) {
            float4 f = *reinterpret_cast<const float4*>(v + (size_t)n * ROW_F + e);
            __half2 h0 = __floats2half2_rn(f.x, f.y);
            __half2 h1 = __floats2half2_rn(f.z, f.w);
            w2.x = *reinterpret_cast<unsigned int*>(&h0);
            w2.y = *reinterpret_cast<unsigned int*>(&h1);
        }
        o[(size_t)n * ROW_U2 + r] = w2;
    }
}

// ---------------- main kernel: one wave per batch row (round-10 champion) ---
// Row image: 320 half2; element d = (field f = d>>3, k-pair j = d&7).
// Lane l owns d = l + 64m (m=0..4): exactly 5 half2, all with j = l&7.
// xor-orbit {8,16,32} of lane l covers all 40 fields once per k-pair ->
// stage-1 shuffles give S(j),Q(j) per lane; stage-2 {1,2,4} sums j-groups.
// Sparse loop: 4 features per group -> 20 independent dword loads in flight.
// launch_bounds(256,7): 73-VGPR cap = headroom for the 20 load dests while
// keeping 7 waves/SIMD (hard 8-wave cap spilled in round 8; uncapped gave
// 92 VGPR / 5 waves in round 9; 7 is the measured balance point).
__global__ __launch_bounds__(THREADS, 7) void ffm_f16u(
    const float* __restrict__ x,     // [B, 39]
    const float* __restrict__ w,     // [2613]
    const float* __restrict__ bias,  // [1]
    const __half2* __restrict__ vb,  // [2613, 320] padded half2 rows
    float* __restrict__ out,         // [B]
    int B)
{
    __shared__ __half2 ldsDense[N_DENSE * ROW_DW];   // 16640 B
    {
        const uint4* src = reinterpret_cast<const uint4*>(vb);
        uint4* dst = reinterpret_cast<uint4*>(ldsDense);
        for (int i = threadIdx.x; i < N_DENSE * ROW_DW / 4; i += THREADS)
            dst[i] = src[i];
    }
    __syncthreads();

    const int l = threadIdx.x & 63;
    // wave-uniform wave id -> uniform row -> x reads become s_loads
    const int wv = __builtin_amdgcn_readfirstlane((int)(threadIdx.x >> 6));
    const int row = blockIdx.x * ROWS_PER_BLOCK + wv;
    if (row >= B) return;

    const float* xr = x + (size_t)row * N_FIELD;

    __half2 acc[5];
#pragma unroll
    for (int m = 0; m < 5; ++m) acc[m] = __floats2half2_rn(0.f, 0.f);

    float lin = bias[0];

    // ---- dense features (LDS broadcast, uniform xv; fold linear part) ----
#pragma unroll
    for (int j = 0; j < N_DENSE; ++j) {
        float xv = xr[j];
        lin = fmaf(xv, w[j], lin);
        __half2 xh = __float2half2_rn(xv);
#pragma unroll
        for (int m = 0; m < 5; ++m)
            acc[m] = __hfma2(xh, ldsDense[j * ROW_DW + 64 * m + l], acc[m]);
    }

    // ---- sparse gathers: 4 features/group, 20 dword loads in flight ----
#pragma unroll
    for (int s = 0; s < 24; s += 4) {
        int i0 = N_DENSE + (s    ) * SPARSE_DIM + (int)xr[N_DENSE + s    ];
        int i1 = N_DENSE + (s + 1) * SPARSE_DIM + (int)xr[N_DENSE + s + 1];
        int i2 = N_DENSE + (s + 2) * SPARSE_DIM + (int)xr[N_DENSE + s + 2];
        int i3 = N_DENSE + (s + 3) * SPARSE_DIM + (int)xr[N_DENSE + s + 3];
        const __half2* b0 = vb + (size_t)i0 * ROW_DW + l;
        const __half2* b1 = vb + (size_t)i1 * ROW_DW + l;
        const __half2* b2 = vb + (size_t)i2 * ROW_DW + l;
        const __half2* b3 = vb + (size_t)i3 * ROW_DW + l;
        __half2 t00 = b0[0], t01 = b0[64], t02 = b0[128], t03 = b0[192], t04 = b0[256];
        __half2 t10 = b1[0], t11 = b1[64], t12 = b1[128], t13 = b1[192], t14 = b1[256];
        __half2 t20 = b2[0], t21 = b2[64], t22 = b2[128], t23 = b2[192], t24 = b2[256];
        __half2 t30 = b3[0], t31 = b3[64], t32 = b3[128], t33 = b3[192], t34 = b3[256];
        lin += w[i0] + w[i1] + w[i2] + w[i3];
        acc[0] = __hadd2(acc[0], t00); acc[1] = __hadd2(acc[1], t01);
        acc[2] = __hadd2(acc[2], t02); acc[3] = __hadd2(acc[3], t03);
        acc[4] = __hadd2(acc[4], t04);
        acc[0] = __hadd2(acc[0], t10); acc[1] = __hadd2(acc[1], t11);
        acc[2] = __hadd2(acc[2], t12); acc[3] = __hadd2(acc[3], t13);
        acc[4] = __hadd2(acc[4], t14);
        acc[0] = __hadd2(acc[0], t20); acc[1] = __hadd2(acc[1], t21);
        acc[2] = __hadd2(acc[2], t22); acc[3] = __hadd2(acc[3], t23);
        acc[4] = __hadd2(acc[4], t24);
        acc[0] = __hadd2(acc[0], t30); acc[1] = __hadd2(acc[1], t31);
        acc[2] = __hadd2(acc[2], t32); acc[3] = __hadd2(acc[3], t33);
        acc[4] = __hadd2(acc[4], t34);
    }
    {   // tail pair: s = 24, 25
        int i0 = N_DENSE + 24 * SPARSE_DIM + (int)xr[N_DENSE + 24];
        int i1 = N_DENSE + 25 * SPARSE_DIM + (int)xr[N_DENSE + 25];
        const __half2* b0 = vb + (size_t)i0 * ROW_DW + l;
        const __half2* b1 = vb + (size_t)i1 * ROW_DW + l;
        __half2 t00 = b0[0], t01 = b0[64], t02 = b0[128], t03 = b0[192], t04 = b0[256];
        __half2 t10 = b1[0], t11 = b1[64], t12 = b1[128], t13 = b1[192], t14 = b1[256];
        lin += w[i0] + w[i1];
        acc[0] = __hadd2(acc[0], t00); acc[1] = __hadd2(acc[1], t01);
        acc[2] = __hadd2(acc[2], t02); acc[3] = __hadd2(acc[3], t03);
        acc[4] = __hadd2(acc[4], t04);
        acc[0] = __hadd2(acc[0], t10); acc[1] = __hadd2(acc[1], t11);
        acc[2] = __hadd2(acc[2], t12); acc[3] = __hadd2(acc[3], t13);
        acc[4] = __hadd2(acc[4], t14);
    }

    // ---- reduction (f32) ----
    float sx = 0.f, sy = 0.f, qx = 0.f, qy = 0.f;
#pragma unroll
    for (int m = 0; m < 5; ++m) {
        float ax = __low2float(acc[m]);
        float ay = __high2float(acc[m]);
        sx += ax; sy += ay;
        qx = fmaf(ax, ax, qx);
        qy = fmaf(ay, ay, qy);
    }
#pragma unroll
    for (int mask = 8; mask <= 32; mask <<= 1) {
        sx += __shfl_xor(sx, mask);
        sy += __shfl_xor(sy, mask);
        qx += __shfl_xor(qx, mask);
        qy += __shfl_xor(qy, mask);
    }
    float c = (sx * sx - qx) + (sy * sy - qy);
    c += __shfl_xor(c, 1);
    c += __shfl_xor(c, 2);
    c += __shfl_xor(c, 4);

    float logit = lin + 0.5f * c;
    if (l == 0) out[row] = 1.f / (1.f + expf(-logit));
}

// ---------------- fp32 fallback (round-1 kernel, 16 lanes/row) --------------
#define ROW_Q (ROW_F / 4)
__global__ __launch_bounds__(256) void ffm_fp32(
    const float* __restrict__ x, const float* __restrict__ w,
    const float* __restrict__ bias, const float* __restrict__ v,
    float* __restrict__ out, int B)
{
    __shared__ float ldsDense[N_DENSE * ROW_F];
    const float4* v4 = reinterpret_cast<const float4*>(v);
    float4* lds4 = reinterpret_cast<float4*>(ldsDense);
    for (int i = threadIdx.x; i < N_DENSE * ROW_Q; i += 256) lds4[i] = v4[i];
    __syncthreads();

    const int g = threadIdx.x >> 4, l = threadIdx.x & 15;
    const int row = blockIdx.x * 16 + g;
    if (row >= B) return;
    const float* xr = x + row * (N_DENSE + N_SPARSE);

    float4 acc[10];
#pragma unroll
    for (int i = 0; i < 10; ++i) acc[i] = make_float4(0.f, 0.f, 0.f, 0.f);
#pragma unroll
    for (int j = 0; j < N_DENSE; ++j) {
        float xv = xr[j];
        const float4* b = lds4 + j * ROW_Q;
#pragma unroll
        for (int i = 0; i < 10; ++i)
            if (i < 9 || l < 12) {
                float4 tt = b[l + 16 * i];
                acc[i].x += xv * tt.x; acc[i].y += xv * tt.y;
                acc[i].z += xv * tt.z; acc[i].w += xv * tt.w;
            }
    }
    int nidx[N_SPARSE];
#pragma unroll
    for (int s = 0; s < N_SPARSE; ++s)
        nidx[s] = N_DENSE + s * SPARSE_DIM + (int)xr[N_DENSE + s];
    for (int s = 0; s < N_SPARSE; ++s) {
        const float4* b = v4 + (size_t)nidx[s] * ROW_Q;
#pragma unroll
        for (int i = 0; i < 10; ++i)
            if (i < 9 || l < 12) {
                float4 tt = b[l + 16 * i];
                acc[i].x += tt.x; acc[i].y += tt.y; acc[i].z += tt.z; acc[i].w += tt.w;
            }
    }
    float4 s4 = make_float4(0,0,0,0), q4 = make_float4(0,0,0,0);
#pragma unroll
    for (int i = 0; i < 10; ++i) {
        s4.x += acc[i].x; s4.y += acc[i].y; s4.z += acc[i].z; s4.w += acc[i].w;
        q4.x += acc[i].x*acc[i].x; q4.y += acc[i].y*acc[i].y;
        q4.z += acc[i].z*acc[i].z; q4.w += acc[i].w*acc[i].w;
    }
#pragma unroll
    for (int m = 4; m <= 8; m <<= 1) {
        s4.x += __shfl_xor(s4.x,m); s4.y += __shfl_xor(s4.y,m);
        s4.z += __shfl_xor(s4.z,m); s4.w += __shfl_xor(s4.w,m);
        q4.x += __shfl_xor(q4.x,m); q4.y += __shfl_xor(q4.y,m);
        q4.z += __shfl_xor(q4.z,m); q4.w += __shfl_xor(q4.w,m);
    }
    float c = (s4.x*s4.x - q4.x) + (s4.y*s4.y - q4.y) +
              (s4.z*s4.z - q4.z) + (s4.w*s4.w - q4.w);
    c += __shfl_xor(c,1); c += __shfl_xor(c,2);
    float lin = bias[0];
#pragma unroll
    for (int j = 0; j < N_DENSE; ++j) lin += xr[j]*w[j];
#pragma unroll
    for (int s = 0; s < N_SPARSE; ++s) lin += w[nidx[s]];
    float logit = lin + 0.5f*c;
    if (l == 0) out[row] = 1.f/(1.f+expf(-logit));
}

extern "C" void kernel_launch(void* const* d_in, const int* in_sizes, int n_in,
                              void* d_out, int out_size, void* d_ws, size_t ws_size,
                              hipStream_t stream) {
    const float* x    = (const float*)d_in[0];
    const float* w    = (const float*)d_in[1];
    const float* bias = (const float*)d_in[2];
    const float* v    = (const float*)d_in[3];
    float* out = (float*)d_out;

    int B = in_sizes[0] / (N_DENSE + N_SPARSE);
    size_t need = (size_t)N_FEATURES * ROW_DW * sizeof(__half2);  // 3,344,640 B

    if (ws_size >= need) {
        int cvt_grid = (CVT_TOTAL + 255) / 256;   // 1634 blocks
        cvt_pad_f16v<<<cvt_grid, 256, 0, stream>>>(v, (uint2*)d_ws);
        int grid = (B + ROWS_PER_BLOCK - 1) / ROWS_PER_BLOCK;
        ffm_f16u<<<grid, THREADS, 0, stream>>>(
            x, w, bias, (const __half2*)d_ws, out, B);
    } else {
        int grid = (B + 15) / 16;
        ffm_fp32<<<grid, 256, 0, stream>>>(x, w, bias, v, out, B);
    }
}